// Round 6
// baseline (3781.062 us; speedup 1.0000x reference)
//
#include <hip/hip_runtime.h>

#define NB   8
#define NPB  4              // producer blocks (2 batches each)
#define NP   8192
#define NS   2048
#define NK   16
#define DIN  64
#define DOUT 128
#define BN_EPS 1e-5f

#define MT   1024           // block size (16 waves)
#define NW   252            // worker blocks: 4 + 252 = 256 = CU count
#define GT   512            // threads per producer group
#define FP   (NP / GT)      // 16 fps points per thread
#define GW   (GT / 64)      // 8 waves per group
#define KJ   (NP / MT)      // 8 knn points per thread
#define KBINS 64
#define MAXC 512

typedef unsigned long long ull;

// ---------------- K0: fold BN into weights, transpose to [k][o] ----------------
__global__ void fold_weights_kernel(const float* __restrict__ W, const float* __restrict__ bias,
                                    const float* __restrict__ gamma, const float* __restrict__ beta,
                                    const float* __restrict__ rmean, const float* __restrict__ rvar,
                                    float* __restrict__ Wt, float* __restrict__ Cb)
{
    int i = blockIdx.x * 256 + threadIdx.x;
    if (i < DIN * DOUT) {
        int o = i & (DOUT - 1);
        int k = i >> 7;
        float sc = gamma[o] * rsqrtf(rvar[o] + BN_EPS);
        Wt[i] = W[o * DIN + k] * sc;            // Wt[k*128 + o]
        if (i < DOUT) {
            Cb[i] = (bias[i] - rmean[i]) * sc + beta[i];
        }
    }
}

// ---------------- f64-packed argmax helpers --------------------------------------
// packed u64 = (fp32 dist bits << 32) | ~idx, as double (sign bit 0 -> numeric
// order == u64 order): fmax == (max dist, tie -> min idx).
template<int CTRL, int RMASK>
__device__ __forceinline__ double dpp_max_f64(double v)
{
    unsigned long long u = (unsigned long long)__double_as_longlong(v);
    unsigned hi = (unsigned)(u >> 32), lo = (unsigned)u;
    unsigned th = (unsigned)__builtin_amdgcn_update_dpp((int)hi, (int)hi, CTRL, RMASK, 0xF, false);
    unsigned tl = (unsigned)__builtin_amdgcn_update_dpp((int)lo, (int)lo, CTRL, RMASK, 0xF, false);
    double o = __longlong_as_double((long long)(((unsigned long long)th << 32) | tl));
    return fmax(v, o);
}

__device__ __forceinline__ float max3f(float a, float b, float c)
{
    return fmaxf(fmaxf(a, b), c);   // clang fuses to v_max3_f32 (exact, associative)
}

__device__ __forceinline__ int knn_bin(float d)
{
    int e = (int)(__float_as_uint(d) >> 23) - 90;   // monotone, clamped octave bins
    return e < 0 ? 0 : (e > 63 ? 63 : e);
}

// ---------------- mega kernel: 4 dual-batch fps producers + 252 workers --------
struct FpsS {
    ull part[2][2][GW];                 // [group][step&1][wave] packed partials
    unsigned arr[2][2];                 // [group][step&1] arrival counters
};
struct KnnS {
    float sdist[NP];                    // 32 KB
    unsigned hist[KBINS][33];           // [bin][c] +pad: atomic bank=(bin+c)%32, conflict-free
    float cd[MAXC];
    int   ci[MAXC];
    int   sidx[NK];
    float sf[NK][DIN];                  // 4 KB gathered feat rows
    float red[8][DOUT];                 // 4 KB cross-group max
    unsigned ccnt;
    int cut;
};
union MegaS { FpsS f; KnnS k; char pad_[90112]; };
// pad -> 88 KB LDS: exactly 1 block/CU; grid 256 -> all blocks co-resident,
// so producer progress never depends on dispatch order (deadlock-safe).

__global__ __launch_bounds__(MT, 1)
void mega_kernel(const float* __restrict__ coords, float* __restrict__ out_coords,
                 const float* __restrict__ feat, const float* __restrict__ Wt,
                 const float* __restrict__ Cb, float* __restrict__ outF,
                 unsigned* __restrict__ flags)
{
#pragma clang fp contract(off)
    __shared__ MegaS smem;
    const int t = threadIdx.x;

    if (blockIdx.x < NPB) {
        // ========== FPS producer: 2 independent 8-wave groups per block =====
        // No block barrier in the loop: each group syncs via a lock-free LDS
        // counter barrier (write partial -> release-add; acquire-poll). The
        // two groups drift to different phases, so one group's serial-chain
        // stalls are filled by the other group's issue on the same SIMDs.
        const int g    = t >> 9;               // group 0/1
        const int tg   = t & (GT - 1);         // thread-in-group
        const int b    = blockIdx.x * 2 + g;   // batch 0..7
        const int wv   = tg >> 6;              // wave-in-group 0..7
        const int lane = t & 63;
        const float* cb = coords + (size_t)b * NP * 3;

        if (t < 8) ((unsigned*)smem.f.arr)[t] = 0;
        __syncthreads();                       // one-time: counters visible

        // points live in registers; same lane->point map as the verified r0
        // kernel (i = tg + k*512), so selections are bit-identical.
        float px[FP], py[FP], pz[FP], dist[FP];
#pragma unroll
        for (int k = 0; k < FP; ++k) {
            int i = tg + k * GT;
            px[k] = cb[i * 3 + 0]; py[k] = cb[i * 3 + 1]; pz[k] = cb[i * 3 + 2];
            dist[k] = 1e10f;
        }
        float cx = cb[0], cy = cb[1], cz = cb[2];   // selection 0 = point 0
        float rx = 0.f, ry = 0.f, rz = 0.f;         // publish latch (wave 0)
        const unsigned ntg = ~(unsigned)tg;         // ~(tg + k*GT) == ntg - (k<<9)

        for (int s = 0; s < NS; ++s) {
            // latch selection s coords for the granule publish
            if (wv == 0 && lane == (s & 31)) { rx = cx; ry = cy; rz = cz; }

            // min-dist update over 16 register-resident points
#pragma unroll
            for (int k = 0; k < FP; ++k) {
                float dx = px[k] - cx, dy = py[k] - cy, dz = pz[k] - cz;
                float d = fmaf(dz, dz, fmaf(dy, dy, dx * dx));
                dist[k] = fminf(dist[k], d);
            }
            // max of 16 via v_max3 tree (exact; max associative)
            float a0 = max3f(dist[0],  dist[1],  dist[2]);
            float a1 = max3f(dist[3],  dist[4],  dist[5]);
            float a2 = max3f(dist[6],  dist[7],  dist[8]);
            float a3 = max3f(dist[9],  dist[10], dist[11]);
            float a4 = max3f(dist[12], dist[13], dist[14]);
            float m  = fmaxf(max3f(a0, a1, a2), max3f(a3, a4, dist[15]));
            // smallest k attaining m: two parallel 8-deep descending chains
            int kA = 99, kB = 99;
#pragma unroll
            for (int k = 7; k >= 0; --k)
                if (dist[k] == m) kA = k;
#pragma unroll
            for (int k = 15; k >= 8; --k)
                if (dist[k] == m) kB = k;
            const int kk = (kA != 99) ? kA : kB;
            double best = __longlong_as_double(
                (long long)(((ull)__float_as_uint(m) << 32) | (ntg - (unsigned)(kk << 9))));

            // wave argmax: 6 DPP f64-max levels -> lane 63 holds wave max
            best = dpp_max_f64<0xB1,  0xF>(best);  // quad_perm xor1
            best = dpp_max_f64<0x4E,  0xF>(best);  // quad_perm xor2
            best = dpp_max_f64<0x124, 0xF>(best);  // row_ror:4
            best = dpp_max_f64<0x128, 0xF>(best);  // row_ror:8
            best = dpp_max_f64<0x142, 0xA>(best);  // row_bcast15
            best = dpp_max_f64<0x143, 0xC>(best);  // row_bcast31

            const int pb = s & 1;
            if (lane == 63) {
                smem.f.part[g][pb][wv] = (ull)__double_as_longlong(best);
                __hip_atomic_fetch_add(&smem.f.arr[g][pb], 1u,
                                       __ATOMIC_RELEASE, __HIP_MEMORY_SCOPE_WORKGROUP);
            }
            // group barrier: all 8 waves arrived for this pb.
            // WAR-safe: reaching step s+2's write requires passing poll(s+1),
            // which orders after every wave's reads of buffer pb at step s.
            const unsigned tgt = (unsigned)(GW) * ((unsigned)(s >> 1) + 1u);
            while (__hip_atomic_load(&smem.f.arr[g][pb],
                                     __ATOMIC_ACQUIRE, __HIP_MEMORY_SCOPE_WORKGROUP) < tgt) {}

            // cross-wave: read partial[lane&7], 3 DPP levels (period-8 values)
            double gg = __longlong_as_double((long long)smem.f.part[g][pb][lane & 7]);
            gg = dpp_max_f64<0xB1,  0xF>(gg);
            gg = dpp_max_f64<0x4E,  0xF>(gg);
            gg = dpp_max_f64<0x124, 0xF>(gg);
            const unsigned iw = ~(unsigned)(ull)__double_as_longlong(gg);

            // next centroid coords: L2-resident broadcast load
            cx = cb[iw * 3 + 0]; cy = cb[iw * 3 + 1]; cz = cb[iw * 3 + 2];

            // publish a 32-query granule from wave-0 latch registers
            if ((s & 31) == 31) {
                if (tg < 32) {
                    float* dst = out_coords + ((size_t)b * NS + (s - 31) + tg) * 3;
                    dst[0] = rx; dst[1] = ry; dst[2] = rz;
                }
                if (tg == 0)                   // release covers wave 0's stores
                    __hip_atomic_store(&flags[b * 16], (unsigned)((s + 1) >> 5),
                                       __ATOMIC_RELEASE, __HIP_MEMORY_SCOPE_AGENT);
            }
        }
    } else {
        // ===== persistent worker: knn + fused gather/MLP/max per query =====
        const int wid = blockIdx.x - NPB;          // 0..251
        const int c = t & 31;
        const int o = t & (DOUT - 1);
        const int grp = t >> 7;                    // 0..7
        const int lane = t & 63;

        for (int j = wid; j < NB * NS; j += NW) {
            const int s = j >> 3, b = j & 7;       // ascending s per worker
            const int q = b * NS + s;

            if (t == 0) {
                const unsigned need = (unsigned)(s >> 5) + 1;
                while (__hip_atomic_load(&flags[b * 16], __ATOMIC_ACQUIRE,
                                         __HIP_MEMORY_SCOPE_AGENT) < need)
                    __builtin_amdgcn_s_sleep(32);
            }
            __syncthreads();

            const float* cb = coords + (size_t)b * NP * 3;
            const float* qp = out_coords + (size_t)q * 3;
            const float qx = qp[0], qy = qp[1], qz = qp[2];

            for (int i = t; i < KBINS * 33; i += MT) ((unsigned*)smem.k.hist)[i] = 0;
            if (t == 0) smem.k.ccnt = 0;
            __syncthreads();

            for (int jj = 0; jj < KJ; ++jj) {
                int i = t + jj * MT;
                float dx = cb[i * 3 + 0] - qx, dy = cb[i * 3 + 1] - qy, dz = cb[i * 3 + 2] - qz;
                float d = fmaf(dz, dz, fmaf(dy, dy, dx * dx));
                smem.k.sdist[i] = d;
                atomicAdd(&smem.k.hist[knn_bin(d)][c], 1u);
            }
            __syncthreads();

            if (t < 64) {
                unsigned total = 0;
#pragma unroll
                for (int cc = 0; cc < 32; ++cc) total += smem.k.hist[t][cc];
                unsigned incl = total;
#pragma unroll
                for (int off = 1; off < 64; off <<= 1) {
                    unsigned n = __shfl_up(incl, off);
                    if (t >= off) incl += n;
                }
                unsigned excl = incl - total;
                if (excl < NK && incl >= NK) smem.k.cut = t;
            }
            __syncthreads();

            const int cut = smem.k.cut;
            for (int jj = 0; jj < KJ; ++jj) {
                int i = t + jj * MT;
                float d = smem.k.sdist[i];
                bool take = knn_bin(d) <= cut;
                unsigned long long mk = __ballot(take);
                unsigned base = 0;
                if (lane == 0 && mk)
                    base = atomicAdd(&smem.k.ccnt, (unsigned)__popcll(mk));
                base = __shfl(base, 0);
                if (take) {
                    unsigned p = base + (unsigned)__popcll(mk & ((1ull << lane) - 1ull));
                    if (p < MAXC) { smem.k.cd[p] = d; smem.k.ci[p] = i; }
                }
            }
            __syncthreads();

            // parallel rank-select: rank = #{(dj,ij) < (d,i)}; unique ranks -> LDS
            int cnt = (int)(smem.k.ccnt < (unsigned)MAXC ? smem.k.ccnt : (unsigned)MAXC);
            for (int p = t; p < cnt; p += MT) {
                float d = smem.k.cd[p]; int idx = smem.k.ci[p];
                int rank = 0;
                for (int jj = 0; jj < cnt; ++jj) {
                    float dj = smem.k.cd[jj]; int ij = smem.k.ci[jj];
                    rank += (dj < d || (dj == d && ij < idx)) ? 1 : 0;
                }
                if (rank < NK) smem.k.sidx[rank] = idx;
            }
            __syncthreads();

            // gather 16 neighbor feat rows (coalesced 256-B rows, single pass)
            {
                int row = t >> 6;                  // 0..15
                smem.k.sf[row][t & 63] =
                    feat[((size_t)b * NP + smem.k.sidx[row]) * DIN + (t & 63)];
            }
            __syncthreads();

            // fused MLP+relu+max: thread handles out-channel o, neighbors
            // {grp, grp+8}; cross-group max via LDS
            const float cb0 = Cb[o];
            float mx = -3.4e38f;
#pragma unroll
            for (int nn = 0; nn < 2; ++nn) {
                const float4* f4 = (const float4*)smem.k.sf[grp + nn * 8];
                float acc = cb0;
#pragma unroll
                for (int k4 = 0; k4 < DIN / 4; ++k4) {
                    float4 f = f4[k4];
                    acc = fmaf(f.x, Wt[(k4 * 4 + 0) * DOUT + o], acc);
                    acc = fmaf(f.y, Wt[(k4 * 4 + 1) * DOUT + o], acc);
                    acc = fmaf(f.z, Wt[(k4 * 4 + 2) * DOUT + o], acc);
                    acc = fmaf(f.w, Wt[(k4 * 4 + 3) * DOUT + o], acc);
                }
                mx = fmaxf(mx, fmaxf(acc, 0.0f));
            }
            smem.k.red[grp][o] = mx;
            __syncthreads();

            if (t < DOUT) {
                float v0 = max3f(smem.k.red[0][t], smem.k.red[1][t], smem.k.red[2][t]);
                float v1 = max3f(smem.k.red[3][t], smem.k.red[4][t], smem.k.red[5][t]);
                float v  = max3f(v0, v1, fmaxf(smem.k.red[6][t], smem.k.red[7][t]));
                outF[(size_t)q * DOUT + t] = v;
            }
            __syncthreads();
        }
    }
}

extern "C" void kernel_launch(void* const* d_in, const int* in_sizes, int n_in,
                              void* d_out, int out_size, void* d_ws, size_t ws_size,
                              hipStream_t stream)
{
    const float* coords = (const float*)d_in[0];
    const float* feat   = (const float*)d_in[1];
    const float* W      = (const float*)d_in[2];
    const float* bias   = (const float*)d_in[3];
    const float* gamma  = (const float*)d_in[4];
    const float* beta   = (const float*)d_in[5];
    const float* rmean  = (const float*)d_in[6];
    const float* rvar   = (const float*)d_in[7];

    float* out_coords = (float*)d_out;                    // [8,2048,3]
    float* out_feat   = out_coords + (size_t)NB * NS * 3; // [8,2048,128]

    char* ws = (char*)d_ws;
    float*    Wt    = (float*)ws;                         // 32 KB
    float*    Cb    = (float*)(ws + 32768);               // 512 B
    unsigned* flags = (unsigned*)(ws + 40960);            // 8 flags, 64B apart

    hipMemsetAsync(flags, 0, 8 * 16 * sizeof(unsigned), stream);
    fold_weights_kernel<<<(DIN * DOUT + 255) / 256, 256, 0, stream>>>(
        W, bias, gamma, beta, rmean, rvar, Wt, Cb);
    mega_kernel<<<NPB + NW, MT, 0, stream>>>(
        coords, out_coords, feat, Wt, Cb, out_feat, flags);
}

// Round 7
// 1743.362 us; speedup vs baseline: 2.1688x; 2.1688x over previous
//
#include <hip/hip_runtime.h>

#define NB   8
#define NP   8192
#define NS   2048
#define NK   16
#define DIN  64
#define DOUT 128
#define BN_EPS 1e-5f

#define MT   512            // mega-kernel block size
#define NW   248            // worker blocks (grid = 8 fps + 248 workers = 256 CUs)
#define FP   (NP / MT)      // 16 fps points per thread
#define FW   (MT / 64)      // 8 waves
#define KJ   (NP / MT)      // 16 knn points per thread
#define KBINS 64
#define MAXC 512

typedef unsigned long long ull;

// ---------------- K0: fold BN into weights, transpose to [k][o] ----------------
__global__ void fold_weights_kernel(const float* __restrict__ W, const float* __restrict__ bias,
                                    const float* __restrict__ gamma, const float* __restrict__ beta,
                                    const float* __restrict__ rmean, const float* __restrict__ rvar,
                                    float* __restrict__ Wt, float* __restrict__ Cb)
{
    int i = blockIdx.x * 256 + threadIdx.x;
    if (i < DIN * DOUT) {
        int o = i & (DOUT - 1);
        int k = i >> 7;
        float sc = gamma[o] * rsqrtf(rvar[o] + BN_EPS);
        Wt[i] = W[o * DIN + k] * sc;            // Wt[k*128 + o]
        if (i < DOUT) {
            Cb[i] = (bias[i] - rmean[i]) * sc + beta[i];
        }
    }
}

// ---------------- f64-packed argmax helpers --------------------------------------
// packed u64 = (fp32 dist bits << 32) | ~idx, as double (sign bit 0 -> numeric
// order == u64 order): fmax == (max dist, tie -> min idx).
template<int CTRL, int RMASK>
__device__ __forceinline__ double dpp_max_f64(double v)
{
    unsigned long long u = (unsigned long long)__double_as_longlong(v);
    unsigned hi = (unsigned)(u >> 32), lo = (unsigned)u;
    unsigned th = (unsigned)__builtin_amdgcn_update_dpp((int)hi, (int)hi, CTRL, RMASK, 0xF, false);
    unsigned tl = (unsigned)__builtin_amdgcn_update_dpp((int)lo, (int)lo, CTRL, RMASK, 0xF, false);
    double o = __longlong_as_double((long long)(((unsigned long long)th << 32) | tl));
    return fmax(v, o);
}

__device__ __forceinline__ float max3f(float a, float b, float c)
{
    return fmaxf(fmaxf(a, b), c);   // clang fuses to v_max3_f32 (exact, associative)
}

__device__ __forceinline__ int knn_bin(float d)
{
    int e = (int)(__float_as_uint(d) >> 23) - 90;   // monotone, clamped octave bins
    return e < 0 ? 0 : (e > 63 ? 63 : e);
}

// ---------------- mega kernel: 8 fps producers + 248 persistent workers --------
struct FpsS {
    float4 sxyz[NP];                    // 128 KB, immutable after staging
    int sel[NS];                        // 8 KB
    ull slot[3];                        // rotating cross-wave argmax slots
    // slot rotation safety: between barrier(s-1) and barrier(s) the live
    // accesses are {read slot[(s-1)%3], atomicMax slot[s%3], zero slot[(s+1)%3]}
    // -- pairwise distinct. Zero of slot j (at step j+2 pre-barrier) is
    // separated from reads of slot j (step j post-barrier) by barrier(j+1).
};
struct KnnS {
    float sdist[NP];                    // 32 KB
    unsigned hist[KBINS][33];           // [bin][c] +pad: atomic bank=(bin+c)%32, conflict-free
    float cd[MAXC];
    int   ci[MAXC];
    int   sidx[NK];
    float sf[NK][DIN];                  // 4 KB gathered feat rows
    float red[4][DOUT];                 // 2 KB cross-group max
    unsigned ccnt;
    int cut;
};
union MegaS { FpsS f; KnnS k; };
// union = ~137 KB -> 1 block/CU; grid 256 -> all blocks co-resident,
// so producer progress never depends on dispatch order (deadlock-safe).

__global__ __launch_bounds__(MT, 1)
void mega_kernel(const float* __restrict__ coords, float* __restrict__ out_coords,
                 const float* __restrict__ feat, const float* __restrict__ Wt,
                 const float* __restrict__ Cb, float* __restrict__ outF,
                 unsigned* __restrict__ flags)
{
#pragma clang fp contract(off)
    __shared__ MegaS smem;
    const int t = threadIdx.x;

    if (blockIdx.x < NB) {
        // ================= FPS producer (1 block per batch) =================
        const int b = blockIdx.x;
        const float* cb = coords + (size_t)b * NP * 3;

        for (int i = t; i < NP; i += MT)
            smem.f.sxyz[i] = make_float4(cb[i * 3 + 0], cb[i * 3 + 1], cb[i * 3 + 2], 0.0f);
        if (t < 3) smem.f.slot[t] = 0ull;
        __syncthreads();

        float px[FP], py[FP], pz[FP], dist[FP];
#pragma unroll
        for (int k = 0; k < FP; ++k) {
            float4 p = smem.f.sxyz[t + k * MT];
            px[k] = p.x; py[k] = p.y; pz[k] = p.z;
            dist[k] = 1e10f;
        }

        const int wave = t >> 6, lane = t & 63;
        const unsigned nt = ~(unsigned)t;          // ~(t + k*MT) == nt - k*MT
        int cur = 0;
        int si = 0, zi = 1;                        // si = s%3, zi = (s+1)%3
        float4 cc = smem.f.sxyz[0];                // selection 0 = point 0

        for (int s = 0; s < NS; ++s) {
            if (t == 0) smem.f.sel[s] = cur;
            const float cx = cc.x, cy = cc.y, cz = cc.z;

            // min-dist update + f32 dual-chain max (full-rate, no per-point pack)
            float m0 = -1.0f, m1 = -1.0f;
#pragma unroll
            for (int k = 0; k < FP; ++k) {
                float dx = px[k] - cx, dy = py[k] - cy, dz = pz[k] - cz;
                float d = fmaf(dz, dz, fmaf(dy, dy, dx * dx));
                float nd = fminf(dist[k], d);
                dist[k] = nd;
                if (k & 1) m1 = fmaxf(m1, nd);
                else       m0 = fmaxf(m0, nd);
            }
            float m = fmaxf(m0, m1);
            // smallest k attaining m: two parallel 8-deep descending chains
            int kA = 99, kB = 99;
#pragma unroll
            for (int k = 7; k >= 0; --k)
                if (dist[k] == m) kA = k;
#pragma unroll
            for (int k = 15; k >= 8; --k)
                if (dist[k] == m) kB = k;
            const int kk = (kA != 99) ? kA : kB;   // lower half has priority
            double best = __longlong_as_double(
                (long long)(((ull)__float_as_uint(m) << 32) | (nt - (unsigned)(kk * MT))));

            // wave argmax: 6 DPP f64-max levels -> lane 63 holds wave max
            best = dpp_max_f64<0xB1,  0xF>(best);  // quad_perm xor1
            best = dpp_max_f64<0x4E,  0xF>(best);  // quad_perm xor2
            best = dpp_max_f64<0x124, 0xF>(best);  // row_ror:4
            best = dpp_max_f64<0x128, 0xF>(best);  // row_ror:8
            best = dpp_max_f64<0x142, 0xA>(best);  // row_bcast15
            best = dpp_max_f64<0x143, 0xC>(best);  // row_bcast31

            if (lane == 63) {
                // cross-wave join: one LDS atomic per wave (8/step); packs are
                // unique (~idx), so the max is order-independent == DPP result
                atomicMax((ull*)&smem.f.slot[si], (ull)__double_as_longlong(best));
                if (wave == 7) smem.f.slot[zi] = 0ull;   // pre-zero next slot
            }
            __syncthreads();

            // broadcast read of the winning pack (same address, conflict-free)
            const ull gp = smem.f.slot[si];
            cur = (int)~(unsigned)gp;
            cc = smem.f.sxyz[cur];
            si = zi; zi = (zi == 2) ? 0 : zi + 1;

            // publish a 32-query granule (wave 0 only: program-order release
            // covers the wave's own coord stores)
            if ((s & 31) == 31) {
                int base = s - 31;
                if (t < 32) {
                    float4 p = smem.f.sxyz[smem.f.sel[base + t]];
                    float* dst = out_coords + ((size_t)b * NS + base + t) * 3;
                    dst[0] = p.x; dst[1] = p.y; dst[2] = p.z;
                }
                if (t == 0)
                    __hip_atomic_store(&flags[b * 16], (unsigned)((s + 1) >> 5),
                                       __ATOMIC_RELEASE, __HIP_MEMORY_SCOPE_AGENT);
            }
        }
    } else {
        // ===== persistent worker: knn + fused gather/MLP/max per query =====
        const int wid = blockIdx.x - NB;           // 0..247
        const int c = t & 31;
        const int o = t & (DOUT - 1);
        const int grp = t >> 7;                    // 0..3
        const int lane = t & 63;

        for (int j = wid; j < NB * NS; j += NW) {
            const int s = j >> 3, b = j & 7;       // ascending s per worker
            const int q = b * NS + s;

            if (t == 0) {
                const unsigned need = (unsigned)(s >> 5) + 1;
                while (__hip_atomic_load(&flags[b * 16], __ATOMIC_ACQUIRE,
                                         __HIP_MEMORY_SCOPE_AGENT) < need)
                    __builtin_amdgcn_s_sleep(32);
            }
            __syncthreads();

            const float* cb = coords + (size_t)b * NP * 3;
            const float* qp = out_coords + (size_t)q * 3;
            const float qx = qp[0], qy = qp[1], qz = qp[2];

            for (int i = t; i < KBINS * 33; i += MT) ((unsigned*)smem.k.hist)[i] = 0;
            if (t == 0) smem.k.ccnt = 0;
            __syncthreads();

            for (int jj = 0; jj < KJ; ++jj) {
                int i = t + jj * MT;
                float dx = cb[i * 3 + 0] - qx, dy = cb[i * 3 + 1] - qy, dz = cb[i * 3 + 2] - qz;
                float d = fmaf(dz, dz, fmaf(dy, dy, dx * dx));
                smem.k.sdist[i] = d;
                atomicAdd(&smem.k.hist[knn_bin(d)][c], 1u);
            }
            __syncthreads();

            if (t < 64) {
                unsigned total = 0;
#pragma unroll
                for (int cc2 = 0; cc2 < 32; ++cc2) total += smem.k.hist[t][cc2];
                unsigned incl = total;
#pragma unroll
                for (int off = 1; off < 64; off <<= 1) {
                    unsigned n = __shfl_up(incl, off);
                    if (t >= off) incl += n;
                }
                unsigned excl = incl - total;
                if (excl < NK && incl >= NK) smem.k.cut = t;
            }
            __syncthreads();

            const int cut = smem.k.cut;
            for (int jj = 0; jj < KJ; ++jj) {
                int i = t + jj * MT;
                float d = smem.k.sdist[i];
                bool take = knn_bin(d) <= cut;
                unsigned long long mk = __ballot(take);
                unsigned base = 0;
                if (lane == 0 && mk)
                    base = atomicAdd(&smem.k.ccnt, (unsigned)__popcll(mk));
                base = __shfl(base, 0);
                if (take) {
                    unsigned p = base + (unsigned)__popcll(mk & ((1ull << lane) - 1ull));
                    if (p < MAXC) { smem.k.cd[p] = d; smem.k.ci[p] = i; }
                }
            }
            __syncthreads();

            // parallel rank-select: rank = #{(dj,ij) < (d,i)}; unique ranks -> LDS
            int cnt = (int)(smem.k.ccnt < (unsigned)MAXC ? smem.k.ccnt : (unsigned)MAXC);
            for (int p = t; p < cnt; p += MT) {
                float d = smem.k.cd[p]; int idx = smem.k.ci[p];
                int rank = 0;
                for (int jj = 0; jj < cnt; ++jj) {
                    float dj = smem.k.cd[jj]; int ij = smem.k.ci[jj];
                    rank += (dj < d || (dj == d && ij < idx)) ? 1 : 0;
                }
                if (rank < NK) smem.k.sidx[rank] = idx;
            }
            __syncthreads();

            // gather 16 neighbor feat rows (coalesced 256-B rows)
#pragma unroll
            for (int rr = 0; rr < 2; ++rr) {
                int row = (t >> 6) + rr * 8;       // 0..15
                smem.k.sf[row][t & 63] =
                    feat[((size_t)b * NP + smem.k.sidx[row]) * DIN + (t & 63)];
            }
            __syncthreads();

            // fused MLP+relu+max: each thread handles out-channel o, neighbors
            // {grp, grp+4, grp+8, grp+12}; cross-group max via LDS
            const float cb0 = Cb[o];
            float mx = -3.4e38f;
#pragma unroll
            for (int nn = 0; nn < 4; ++nn) {
                const float4* f4 = (const float4*)smem.k.sf[grp + nn * 4];
                float acc = cb0;
#pragma unroll
                for (int k4 = 0; k4 < DIN / 4; ++k4) {
                    float4 f = f4[k4];
                    acc = fmaf(f.x, Wt[(k4 * 4 + 0) * DOUT + o], acc);
                    acc = fmaf(f.y, Wt[(k4 * 4 + 1) * DOUT + o], acc);
                    acc = fmaf(f.z, Wt[(k4 * 4 + 2) * DOUT + o], acc);
                    acc = fmaf(f.w, Wt[(k4 * 4 + 3) * DOUT + o], acc);
                }
                mx = fmaxf(mx, fmaxf(acc, 0.0f));
            }
            smem.k.red[grp][o] = mx;
            __syncthreads();

            if (t < DOUT) {
                float v = fmaxf(fmaxf(smem.k.red[0][t], smem.k.red[1][t]),
                                fmaxf(smem.k.red[2][t], smem.k.red[3][t]));
                outF[(size_t)q * DOUT + t] = v;
            }
            __syncthreads();
        }
    }
}

extern "C" void kernel_launch(void* const* d_in, const int* in_sizes, int n_in,
                              void* d_out, int out_size, void* d_ws, size_t ws_size,
                              hipStream_t stream)
{
    const float* coords = (const float*)d_in[0];
    const float* feat   = (const float*)d_in[1];
    const float* W      = (const float*)d_in[2];
    const float* bias   = (const float*)d_in[3];
    const float* gamma  = (const float*)d_in[4];
    const float* beta   = (const float*)d_in[5];
    const float* rmean  = (const float*)d_in[6];
    const float* rvar   = (const float*)d_in[7];

    float* out_coords = (float*)d_out;                    // [8,2048,3]
    float* out_feat   = out_coords + (size_t)NB * NS * 3; // [8,2048,128]

    char* ws = (char*)d_ws;
    float*    Wt    = (float*)ws;                         // 32 KB
    float*    Cb    = (float*)(ws + 32768);               // 512 B
    unsigned* flags = (unsigned*)(ws + 40960);            // 8 flags, 64B apart

    hipMemsetAsync(flags, 0, 8 * 16 * sizeof(unsigned), stream);
    fold_weights_kernel<<<(DIN * DOUT + 255) / 256, 256, 0, stream>>>(
        W, bias, gamma, beta, rmean, rvar, Wt, Cb);
    mega_kernel<<<NB + NW, MT, 0, stream>>>(
        coords, out_coords, feat, Wt, Cb, out_feat, flags);
}

// Round 8
// 1677.724 us; speedup vs baseline: 2.2537x; 1.0391x over previous
//
#include <hip/hip_runtime.h>

#define NB   8
#define NP   8192
#define NS   2048
#define NK   16
#define DIN  64
#define DOUT 128
#define BN_EPS 1e-5f

#define MT   512            // mega-kernel block size
#define NW   248            // worker blocks (grid = 8 fps + 248 workers = 256 CUs)
#define FP   (NP / MT)      // 16 fps points per thread
#define FW   (MT / 64)      // 8 waves
#define KJ   (NP / MT)      // 16 knn points per thread
#define KBINS 64
#define MAXC 512

typedef unsigned long long ull;

// ---------------- K0: fold BN into weights, transpose to [k][o] ----------------
__global__ void fold_weights_kernel(const float* __restrict__ W, const float* __restrict__ bias,
                                    const float* __restrict__ gamma, const float* __restrict__ beta,
                                    const float* __restrict__ rmean, const float* __restrict__ rvar,
                                    float* __restrict__ Wt, float* __restrict__ Cb)
{
    int i = blockIdx.x * 256 + threadIdx.x;
    if (i < DIN * DOUT) {
        int o = i & (DOUT - 1);
        int k = i >> 7;
        float sc = gamma[o] * rsqrtf(rvar[o] + BN_EPS);
        Wt[i] = W[o * DIN + k] * sc;            // Wt[k*128 + o]
        if (i < DOUT) {
            Cb[i] = (bias[i] - rmean[i]) * sc + beta[i];
        }
    }
}

// ---------------- f64-packed argmax helpers --------------------------------------
// packed u64 = (fp32 dist bits << 32) | ~idx, as double (sign bit 0 -> numeric
// order == u64 order): fmax == (max dist, tie -> min idx).
template<int CTRL, int RMASK>
__device__ __forceinline__ double dpp_max_f64(double v)
{
    unsigned long long u = (unsigned long long)__double_as_longlong(v);
    unsigned hi = (unsigned)(u >> 32), lo = (unsigned)u;
    unsigned th = (unsigned)__builtin_amdgcn_update_dpp((int)hi, (int)hi, CTRL, RMASK, 0xF, false);
    unsigned tl = (unsigned)__builtin_amdgcn_update_dpp((int)lo, (int)lo, CTRL, RMASK, 0xF, false);
    double o = __longlong_as_double((long long)(((unsigned long long)th << 32) | tl));
    return fmax(v, o);
}

__device__ __forceinline__ float max3f(float a, float b, float c)
{
    return fmaxf(fmaxf(a, b), c);   // clang fuses to v_max3_f32 (exact, associative)
}

__device__ __forceinline__ int knn_bin(float d)
{
    int e = (int)(__float_as_uint(d) >> 23) - 90;   // monotone, clamped octave bins
    return e < 0 ? 0 : (e > 63 ? 63 : e);
}

// ---------------- mega kernel: 8 fps producers + 248 persistent workers --------
struct FpsS {
    float4 sxyz[NP];                    // 128 KB, immutable after staging
    unsigned long long rv64[2][FW];     // double-buffered wave partials
};
struct KnnS {
    float sdist[NP];                    // 32 KB
    unsigned hist[KBINS][33];           // [bin][c] +pad: atomic bank=(bin+c)%32, conflict-free
    float cd[MAXC];
    int   ci[MAXC];
    int   sidx[NK];
    float sf[NK][DIN];                  // 4 KB gathered feat rows
    float red[4][DOUT];                 // 2 KB cross-group max
    unsigned ccnt;
    int cut;
};
union MegaS { FpsS f; KnnS k; };
// union = ~131 KB -> 1 block/CU; grid 256 -> all blocks co-resident,
// so producer progress never depends on dispatch order (deadlock-safe).

__global__ __launch_bounds__(MT, 1)
void mega_kernel(const float* __restrict__ coords, float* __restrict__ out_coords,
                 const float* __restrict__ feat, const float* __restrict__ Wt,
                 const float* __restrict__ Cb, float* __restrict__ outF,
                 unsigned* __restrict__ flags)
{
#pragma clang fp contract(off)
    __shared__ MegaS smem;
    const int t = threadIdx.x;

    if (blockIdx.x < NB) {
        // ================= FPS producer (1 block per batch) =================
        const int b = blockIdx.x;
        const float* cb = coords + (size_t)b * NP * 3;

        for (int i = t; i < NP; i += MT)
            smem.f.sxyz[i] = make_float4(cb[i * 3 + 0], cb[i * 3 + 1], cb[i * 3 + 2], 0.0f);
        __syncthreads();

        float px[FP], py[FP], pz[FP], dist[FP];
#pragma unroll
        for (int k = 0; k < FP; ++k) {
            float4 p = smem.f.sxyz[t + k * MT];
            px[k] = p.x; py[k] = p.y; pz[k] = p.z;
            dist[k] = 1e10f;
        }

        const int wave = t >> 6, lane = t & 63;
        const unsigned nt = ~(unsigned)t;          // ~(t + k*MT) == nt - k*MT
        float4 cc = smem.f.sxyz[0];                // selection 0 = point 0
        float rx = 0.f, ry = 0.f, rz = 0.f;        // publish latch (wave 0)

        for (int s = 0; s < NS; ++s) {
            // wave-0 lane (s&31) latches selection s's coords for the publish
            if (wave == 0 && lane == (s & 31)) { rx = cc.x; ry = cc.y; rz = cc.z; }
            const float cx = cc.x, cy = cc.y, cz = cc.z;

            // min-dist update over 16 register-resident points (fmin only)
#pragma unroll
            for (int k = 0; k < FP; ++k) {
                float dx = px[k] - cx, dy = py[k] - cy, dz = pz[k] - cz;
                float d = fmaf(dz, dz, fmaf(dy, dy, dx * dx));
                dist[k] = fminf(dist[k], d);
            }
            // max of 16 via v_max3 tree (exact; max associative) — 7 ops vs 17
            float a0 = max3f(dist[0],  dist[1],  dist[2]);
            float a1 = max3f(dist[3],  dist[4],  dist[5]);
            float a2 = max3f(dist[6],  dist[7],  dist[8]);
            float a3 = max3f(dist[9],  dist[10], dist[11]);
            float a4 = max3f(dist[12], dist[13], dist[14]);
            float m  = fmaxf(max3f(a0, a1, a2), max3f(a3, a4, dist[15]));
            // smallest k attaining m: two parallel 8-deep descending chains
            int kA = 99, kB = 99;
#pragma unroll
            for (int k = 7; k >= 0; --k)
                if (dist[k] == m) kA = k;
#pragma unroll
            for (int k = 15; k >= 8; --k)
                if (dist[k] == m) kB = k;
            const int kk = (kA != 99) ? kA : kB;   // lower half has priority
            double best = __longlong_as_double(
                (long long)(((ull)__float_as_uint(m) << 32) | (nt - (unsigned)(kk * MT))));

            // wave argmax: 6 DPP f64-max levels -> lane 63 holds wave max
            best = dpp_max_f64<0xB1,  0xF>(best);  // quad_perm xor1
            best = dpp_max_f64<0x4E,  0xF>(best);  // quad_perm xor2
            best = dpp_max_f64<0x124, 0xF>(best);  // row_ror:4
            best = dpp_max_f64<0x128, 0xF>(best);  // row_ror:8
            best = dpp_max_f64<0x142, 0xA>(best);  // row_bcast15
            best = dpp_max_f64<0x143, 0xC>(best);  // row_bcast31

            const int pb = s & 1;
            if (lane == 63) smem.f.rv64[pb][wave] = (ull)__double_as_longlong(best);
            __syncthreads();

            // cross-wave: b64 read of partial[lane&7]; period-8 values need
            // only 3 DPP levels (xor1, xor2, ror4) for the max of 8
            double g = __longlong_as_double((long long)smem.f.rv64[pb][lane & 7]);
            g = dpp_max_f64<0xB1,  0xF>(g);
            g = dpp_max_f64<0x4E,  0xF>(g);
            g = dpp_max_f64<0x124, 0xF>(g);
            const int cur = (int)~(unsigned)(ull)__double_as_longlong(g);
            cc = smem.f.sxyz[cur];

            // publish a 32-query granule from wave-0 latch registers
            if ((s & 31) == 31) {
                if (t < 32) {
                    float* dst = out_coords + ((size_t)b * NS + (s - 31) + t) * 3;
                    dst[0] = rx; dst[1] = ry; dst[2] = rz;
                }
                if (t == 0)                        // release covers wave 0's stores
                    __hip_atomic_store(&flags[b * 16], (unsigned)((s + 1) >> 5),
                                       __ATOMIC_RELEASE, __HIP_MEMORY_SCOPE_AGENT);
            }
        }
    } else {
        // ===== persistent worker: knn + fused gather/MLP/max per query =====
        const int wid = blockIdx.x - NB;           // 0..247
        const int c = t & 31;
        const int o = t & (DOUT - 1);
        const int grp = t >> 7;                    // 0..3
        const int lane = t & 63;

        for (int j = wid; j < NB * NS; j += NW) {
            const int s = j >> 3, b = j & 7;       // ascending s per worker
            const int q = b * NS + s;

            if (t == 0) {
                const unsigned need = (unsigned)(s >> 5) + 1;
                while (__hip_atomic_load(&flags[b * 16], __ATOMIC_ACQUIRE,
                                         __HIP_MEMORY_SCOPE_AGENT) < need)
                    __builtin_amdgcn_s_sleep(32);
            }
            __syncthreads();

            const float* cb = coords + (size_t)b * NP * 3;
            const float* qp = out_coords + (size_t)q * 3;
            const float qx = qp[0], qy = qp[1], qz = qp[2];

            for (int i = t; i < KBINS * 33; i += MT) ((unsigned*)smem.k.hist)[i] = 0;
            if (t == 0) smem.k.ccnt = 0;
            __syncthreads();

            for (int jj = 0; jj < KJ; ++jj) {
                int i = t + jj * MT;
                float dx = cb[i * 3 + 0] - qx, dy = cb[i * 3 + 1] - qy, dz = cb[i * 3 + 2] - qz;
                float d = fmaf(dz, dz, fmaf(dy, dy, dx * dx));
                smem.k.sdist[i] = d;
                atomicAdd(&smem.k.hist[knn_bin(d)][c], 1u);
            }
            __syncthreads();

            if (t < 64) {
                unsigned total = 0;
#pragma unroll
                for (int cc2 = 0; cc2 < 32; ++cc2) total += smem.k.hist[t][cc2];
                unsigned incl = total;
#pragma unroll
                for (int off = 1; off < 64; off <<= 1) {
                    unsigned n = __shfl_up(incl, off);
                    if (t >= off) incl += n;
                }
                unsigned excl = incl - total;
                if (excl < NK && incl >= NK) smem.k.cut = t;
            }
            __syncthreads();

            const int cut = smem.k.cut;
            for (int jj = 0; jj < KJ; ++jj) {
                int i = t + jj * MT;
                float d = smem.k.sdist[i];
                bool take = knn_bin(d) <= cut;
                unsigned long long mk = __ballot(take);
                unsigned base = 0;
                if (lane == 0 && mk)
                    base = atomicAdd(&smem.k.ccnt, (unsigned)__popcll(mk));
                base = __shfl(base, 0);
                if (take) {
                    unsigned p = base + (unsigned)__popcll(mk & ((1ull << lane) - 1ull));
                    if (p < MAXC) { smem.k.cd[p] = d; smem.k.ci[p] = i; }
                }
            }
            __syncthreads();

            // parallel rank-select: rank = #{(dj,ij) < (d,i)}; unique ranks -> LDS
            int cnt = (int)(smem.k.ccnt < (unsigned)MAXC ? smem.k.ccnt : (unsigned)MAXC);
            for (int p = t; p < cnt; p += MT) {
                float d = smem.k.cd[p]; int idx = smem.k.ci[p];
                int rank = 0;
                for (int jj = 0; jj < cnt; ++jj) {
                    float dj = smem.k.cd[jj]; int ij = smem.k.ci[jj];
                    rank += (dj < d || (dj == d && ij < idx)) ? 1 : 0;
                }
                if (rank < NK) smem.k.sidx[rank] = idx;
            }
            __syncthreads();

            // gather 16 neighbor feat rows (coalesced 256-B rows)
#pragma unroll
            for (int rr = 0; rr < 2; ++rr) {
                int row = (t >> 6) + rr * 8;       // 0..15
                smem.k.sf[row][t & 63] =
                    feat[((size_t)b * NP + smem.k.sidx[row]) * DIN + (t & 63)];
            }
            __syncthreads();

            // fused MLP+relu+max: each thread handles out-channel o, neighbors
            // {grp, grp+4, grp+8, grp+12}; cross-group max via LDS
            const float cb0 = Cb[o];
            float mx = -3.4e38f;
#pragma unroll
            for (int nn = 0; nn < 4; ++nn) {
                const float4* f4 = (const float4*)smem.k.sf[grp + nn * 4];
                float acc = cb0;
#pragma unroll
                for (int k4 = 0; k4 < DIN / 4; ++k4) {
                    float4 f = f4[k4];
                    acc = fmaf(f.x, Wt[(k4 * 4 + 0) * DOUT + o], acc);
                    acc = fmaf(f.y, Wt[(k4 * 4 + 1) * DOUT + o], acc);
                    acc = fmaf(f.z, Wt[(k4 * 4 + 2) * DOUT + o], acc);
                    acc = fmaf(f.w, Wt[(k4 * 4 + 3) * DOUT + o], acc);
                }
                mx = fmaxf(mx, fmaxf(acc, 0.0f));
            }
            smem.k.red[grp][o] = mx;
            __syncthreads();

            if (t < DOUT) {
                float v = fmaxf(fmaxf(smem.k.red[0][t], smem.k.red[1][t]),
                                fmaxf(smem.k.red[2][t], smem.k.red[3][t]));
                outF[(size_t)q * DOUT + t] = v;
            }
            __syncthreads();
        }
    }
}

extern "C" void kernel_launch(void* const* d_in, const int* in_sizes, int n_in,
                              void* d_out, int out_size, void* d_ws, size_t ws_size,
                              hipStream_t stream)
{
    const float* coords = (const float*)d_in[0];
    const float* feat   = (const float*)d_in[1];
    const float* W      = (const float*)d_in[2];
    const float* bias   = (const float*)d_in[3];
    const float* gamma  = (const float*)d_in[4];
    const float* beta   = (const float*)d_in[5];
    const float* rmean  = (const float*)d_in[6];
    const float* rvar   = (const float*)d_in[7];

    float* out_coords = (float*)d_out;                    // [8,2048,3]
    float* out_feat   = out_coords + (size_t)NB * NS * 3; // [8,2048,128]

    char* ws = (char*)d_ws;
    float*    Wt    = (float*)ws;                         // 32 KB
    float*    Cb    = (float*)(ws + 32768);               // 512 B
    unsigned* flags = (unsigned*)(ws + 40960);            // 8 flags, 64B apart

    hipMemsetAsync(flags, 0, 8 * 16 * sizeof(unsigned), stream);
    fold_weights_kernel<<<(DIN * DOUT + 255) / 256, 256, 0, stream>>>(
        W, bias, gamma, beta, rmean, rvar, Wt, Cb);
    mega_kernel<<<NB + NW, MT, 0, stream>>>(
        coords, out_coords, feat, Wt, Cb, out_feat, flags);
}